// Round 3
// baseline (577.318 us; speedup 1.0000x reference)
//
#include <hip/hip_runtime.h>

#define E_TOTAL 600000
#define NTILES (E_TOTAL / 64)   // 9375
#define TPB 5                   // tiles per block
#define NBLK (NTILES / TPB)     // 1875
#define LDH 264                 // LDS row stride in shorts (528 B, 16B-aligned, bank-spread)

typedef __attribute__((ext_vector_type(8))) short short8;
typedef __attribute__((ext_vector_type(4))) float f32x4;

__device__ __forceinline__ unsigned f2bf_u(float f) {
  union { float f; unsigned u; } v; v.f = f;
  return (v.u + 0x7fffu + ((v.u >> 16) & 1u)) >> 16;  // RNE
}

// LDS-only barrier: drain ds ops, keep global loads in flight.
__device__ __forceinline__ void ldsBarrier() {
  asm volatile("s_waitcnt lgkmcnt(0)\n\ts_barrier" ::: "memory");
}

// ---- prep: x f32 -> bf16 (blocks 0..3124); W1/W2 transpose+cast (blocks 3125..3204) ----
__global__ __launch_bounds__(256) void prep(
    const float* __restrict__ x, const float* __restrict__ W1, const float* __restrict__ W2,
    unsigned short* __restrict__ xb, unsigned short* __restrict__ W1t,
    unsigned short* __restrict__ W2t) {
  __shared__ float t[32][33];
  int bid = blockIdx.x;
  if (bid < 3125) {  // 3125 * 2048 = 6.4M elements of x
    int base = bid * 2048 + threadIdx.x * 8;
    f32x4 a = *(const f32x4*)(x + base);
    f32x4 b = *(const f32x4*)(x + base + 4);
    short8 s;
#pragma unroll
    for (int j = 0; j < 4; ++j) {
      s[j] = (short)f2bf_u(a[j]);
      s[4 + j] = (short)f2bf_u(b[j]);
    }
    *(short8*)(xb + base) = s;
    return;
  }
  bid -= 3125;
  const float* S; unsigned short* D; int k0, n0, N;
  if (bid < 64) { S = W1; D = W1t; N = 256; k0 = (bid >> 3) * 32; n0 = (bid & 7) * 32; }
  else { bid -= 64; S = W2; D = W2t; N = 64; k0 = (bid >> 1) * 32; n0 = (bid & 1) * 32; }
  int tx = threadIdx.x & 31, ty = threadIdx.x >> 5;
#pragma unroll
  for (int i = 0; i < 32; i += 8) t[ty + i][tx] = S[(k0 + ty + i) * N + n0 + tx];
  __syncthreads();
#pragma unroll
  for (int i = 0; i < 32; i += 8)
    D[(n0 + ty + i) * 256 + k0 + tx] = (unsigned short)f2bf_u(t[tx][ty + i]);
}

// ---- fused edge MLP: 5 tiles of 64 edges per block, pipelined gather ----
__global__ __launch_bounds__(256, 3) void edge_mlp(
    const unsigned short* __restrict__ xb, const int* __restrict__ ei,
    const unsigned short* __restrict__ W1t, const unsigned short* __restrict__ W2t,
    const float* __restrict__ b1, const float* __restrict__ b2,
    float* __restrict__ out) {
  __shared__ __align__(16) unsigned short lds[64 * LDH];  // feat tile, reused as hidden
  __shared__ float ldsb1[256];
  __shared__ float ldsb2[64];

  const int tid = threadIdx.x;
  const int lane = tid & 63;
  const int w = tid >> 6;
  const int m = lane & 15;
  const int q = lane >> 4;
  const int* __restrict__ srcI = ei;
  const int* __restrict__ dstI = ei + E_TOTAL;

  // block-invariant loads (issued first in vmcnt queue)
  float b1t = b1[tid];
  float b2t = (tid < 64) ? b2[tid] : 0.f;

  // gather thread mapping: thread handles edges e0+8i, 16B unit ku of the 512B feat row
  const int e0 = tid >> 5;            // 0..7
  const int ku = tid & 31;            // unit 0..31 (0-15 = src half, 16-31 = dst half)
  const int xoff = (ku & 15) * 8;     // shorts into node row
  const int* __restrict__ idxp = (ku < 16) ? srcI : dstI;

  int base = blockIdx.x * (TPB * 64);

  int nds[8];
#pragma unroll
  for (int i = 0; i < 8; ++i) nds[i] = idxp[base + e0 + 8 * i];

  // W2 frags (block-invariant, live in regs all 5 tiles) + W1 offsets
  int w1off[4];
#pragma unroll
  for (int nt = 0; nt < 4; ++nt) w1off[nt] = ((w * 4 + nt) * 16 + m) * 256 + q * 8;
  const int w2o = (w * 16 + m) * 256 + q * 8;
  short8 w2f[8];
#pragma unroll
  for (int j = 0; j < 8; ++j) w2f[j] = *(const short8*)&W2t[w2o + j * 32];

  // prologue gather tile 0 (bf16: one b128 per edge-half)
  short8 g[8];
#pragma unroll
  for (int i = 0; i < 8; ++i) g[i] = *(const short8*)(xb + (long)nds[i] * 128 + xoff);

  ldsb1[tid] = b1t;
  if (tid < 64) ldsb2[tid] = b2t;

#pragma unroll
  for (int i = 0; i < 8; ++i) *(short8*)&lds[(e0 + 8 * i) * LDH + ku * 8] = g[i];

  for (int t = 0; t < TPB; ++t) {
    ldsBarrier();  // feat(t) visible
    const int nbase = base + 64;

    // ---- phase 1: D[n1][e] = W1t-slice @ feat ----
    f32x4 acc[4][4];
#pragma unroll
    for (int nt = 0; nt < 4; ++nt)
#pragma unroll
      for (int mt = 0; mt < 4; ++mt) acc[nt][mt] = (f32x4){0.f, 0.f, 0.f, 0.f};

    short8 wa[2][4];
#pragma unroll
    for (int nt = 0; nt < 4; ++nt) wa[0][nt] = *(const short8*)&W1t[w1off[nt]];

#pragma unroll
    for (int kk = 0; kk < 8; ++kk) {
      const int cur = kk & 1, nxt = cur ^ 1;
      if (kk < 7) {
#pragma unroll
        for (int nt = 0; nt < 4; ++nt)
          wa[nxt][nt] = *(const short8*)&W1t[w1off[nt] + (kk + 1) * 32];
      }
      if (kk == 0 && t < TPB - 1) {  // idx prefetch for t+1 (broadcast loads)
#pragma unroll
        for (int i = 0; i < 8; ++i) nds[i] = idxp[nbase + e0 + 8 * i];
      }
      if (kk == 7 && t < TPB - 1) {  // gather t+1 -> regs (after last W1 load: no drain)
#pragma unroll
        for (int i = 0; i < 8; ++i) g[i] = *(const short8*)(xb + (long)nds[i] * 128 + xoff);
      }
      short8 f[4];
#pragma unroll
      for (int mt = 0; mt < 4; ++mt)
        f[mt] = *(const short8*)&lds[(mt * 16 + m) * LDH + kk * 32 + q * 8];
#pragma unroll
      for (int nt = 0; nt < 4; ++nt)
#pragma unroll
        for (int mt = 0; mt < 4; ++mt)
          acc[nt][mt] = __builtin_amdgcn_mfma_f32_16x16x32_bf16(wa[cur][nt], f[mt], acc[nt][mt], 0, 0, 0);
    }

    ldsBarrier();  // feat reads done; safe to overwrite with hidden

    f32x4 bias[4];
#pragma unroll
    for (int nt = 0; nt < 4; ++nt) bias[nt] = *(const f32x4*)&ldsb1[w * 64 + nt * 16 + q * 4];
#pragma unroll
    for (int nt = 0; nt < 4; ++nt)
#pragma unroll
      for (int mt = 0; mt < 4; ++mt) {
        float h0 = fmaxf(acc[nt][mt][0] + bias[nt][0], 0.f);
        float h1 = fmaxf(acc[nt][mt][1] + bias[nt][1], 0.f);
        float h2 = fmaxf(acc[nt][mt][2] + bias[nt][2], 0.f);
        float h3 = fmaxf(acc[nt][mt][3] + bias[nt][3], 0.f);
        uint2 pk;
        pk.x = f2bf_u(h0) | (f2bf_u(h1) << 16);
        pk.y = f2bf_u(h2) | (f2bf_u(h3) << 16);
        *(uint2*)&lds[(mt * 16 + m) * LDH + w * 64 + nt * 16 + q * 4] = pk;
      }

    ldsBarrier();  // hidden visible

    // ---- phase 2: out = hidden @ W2 + b2 (w2f in regs, VMEM-load-free) ----
    f32x4 acc2[4];
#pragma unroll
    for (int mt = 0; mt < 4; ++mt) acc2[mt] = (f32x4){0.f, 0.f, 0.f, 0.f};
#pragma unroll
    for (int kk = 0; kk < 8; ++kk) {
#pragma unroll
      for (int mt = 0; mt < 4; ++mt) {
        short8 h = *(const short8*)&lds[(mt * 16 + m) * LDH + kk * 32 + q * 8];
        acc2[mt] = __builtin_amdgcn_mfma_f32_16x16x32_bf16(w2f[kk], h, acc2[mt], 0, 0, 0);
      }
    }

    f32x4 b2v = *(const f32x4*)&ldsb2[w * 16 + q * 4];
#pragma unroll
    for (int mt = 0; mt < 4; ++mt) {
      f32x4 o;
#pragma unroll
      for (int r = 0; r < 4; ++r) o[r] = acc2[mt][r] + b2v[r];
      *(f32x4*)&out[(long)(base + mt * 16 + m) * 64 + w * 16 + q * 4] = o;
    }

    ldsBarrier();  // hidden reads done; safe to overwrite with feat(t+1)

    if (t < TPB - 1) {
#pragma unroll
      for (int i = 0; i < 8; ++i) *(short8*)&lds[(e0 + 8 * i) * LDH + ku * 8] = g[i];
      base = nbase;
    }
  }
}

extern "C" void kernel_launch(void* const* d_in, const int* in_sizes, int n_in,
                              void* d_out, int out_size, void* d_ws, size_t ws_size,
                              hipStream_t stream) {
  const float* x  = (const float*)d_in[0];
  const int*   ei = (const int*)d_in[1];
  const float* W1 = (const float*)d_in[2];
  const float* b1 = (const float*)d_in[3];
  const float* W2 = (const float*)d_in[4];
  const float* b2 = (const float*)d_in[5];
  float* out = (float*)d_out;

  unsigned short* W1t = (unsigned short*)d_ws;        // 256*256
  unsigned short* W2t = W1t + 256 * 256;              // 64*256
  unsigned short* xb  = W2t + 64 * 256;               // 50000*128 bf16 = 12.8 MB

  prep<<<3125 + 80, 256, 0, stream>>>(x, W1, W2, xb, W1t, W2t);
  edge_mlp<<<NBLK, 256, 0, stream>>>(xb, ei, W1t, W2t, b1, b2, out);
}